// Round 3
// baseline (292.425 us; speedup 1.0000x reference)
//
#include <hip/hip_runtime.h>

// SpectralMultiHeadAttention on MI355X (gfx950)
// b=4, hw=16384, c=256, heads=8, dh=32.
// Reformulation: S[b] = x^T x (256x256);  G = Wq^T S Wk;  qss = diag(Wq^T S Wq);
// kss = diag(Wk^T S Wk);  A = softmax(G_blocks / (nq nk sqrt(hw)));
// out = x @ (Wv @ Abig^T @ Wout).   q/k/v never materialized.
// R6: (a) k_sgemm grid 128->256 by splitting each block's OUTPUT in half
//     (same K-chain per output -> S bitwise identical) + register prefetch of
//     the next phase's globals under the current phase's MFMA.
//     (b) k_sred+k_gemm_sw+k_fuse+k_gemm_w3 merged into ONE kernel k_mega
//     (grid 256, 131KB LDS -> 1 block/CU, all blocks co-resident) with manual
//     device-scope grid barriers; phase bodies are the old kernels verbatim.
//     3 launches instead of 6; pipeline stays bitwise-identical to R5.

#define B_   4
#define HW_  16384
#define C_   256

typedef __attribute__((ext_vector_type(8))) short short8;
typedef __attribute__((ext_vector_type(4))) float floatx4;

__device__ __forceinline__ unsigned short f2bf(float f) {
  unsigned u = __builtin_bit_cast(unsigned, f);
  u += 0x7FFFu + ((u >> 16) & 1u);          // round-to-nearest-even
  return (unsigned short)(u >> 16);
}

__device__ __forceinline__ void gl_lds16(const unsigned short* g, unsigned short* l) {
  __builtin_amdgcn_global_load_lds(
      (const __attribute__((address_space(1))) unsigned int*)g,
      (__attribute__((address_space(3))) unsigned int*)l, 16, 0, 0);
}

// Grid-wide barrier across 256 co-resident blocks. Counters are zeroed by
// k_sgemm (which completes before k_mega starts, stream-ordered). Release
// fetch_add + acquire polls at AGENT scope handle cross-XCD L2 visibility
// (release -> L2 writeback, acquire -> L2 invalidate). Bounded spin as a
// hang safety-valve (normal wait is ~1e3 polls; bound is 1<<24).
__device__ __forceinline__ void gridbar(unsigned* c) {
  __syncthreads();
  if (threadIdx.x == 0) {
    __hip_atomic_fetch_add(c, 1u, __ATOMIC_RELEASE, __HIP_MEMORY_SCOPE_AGENT);
    for (int spin = 0; spin < (1 << 24); ++spin) {
      if (__hip_atomic_load(c, __ATOMIC_ACQUIRE, __HIP_MEMORY_SCOPE_AGENT) >= 256u) break;
      __builtin_amdgcn_s_sleep(8);
    }
  }
  __syncthreads();
}

// ---------------------------------------------------------------------------
// K2: S partials. grid 256 = b(4)*ks(32)*half(2), 512 thr. Each block stages
// the FULL 256c x 128hw bf16 panel (4 phases over its 512-hw chunk, same bits
// as R5) but computes only a 128-row half of the 256x256 output -> 2x blocks,
// all 256 CUs busy, identical K-chain per output element (S bitwise-same).
// Register prefetch: next phase's 16 float4 issued before current compute.
// ---------------------------------------------------------------------------
__global__ __launch_bounds__(512) void k_sgemm(const float* __restrict__ x,
                                               float* __restrict__ part,
                                               unsigned* __restrict__ bars) {
  if (blockIdx.x == 0 && threadIdx.x < 8)
    __hip_atomic_store(bars + threadIdx.x, 0u, __ATOMIC_RELAXED, __HIP_MEMORY_SCOPE_AGENT);
  __shared__ unsigned short Pt[256 * 128];   // 64 KiB
  int bid = blockIdx.x;
  int hs = bid & 1, ks = (bid >> 1) & 31, b = bid >> 6;
  const float* xv = x + ((size_t)(b * HW_ + ks * 512)) * C_;
  int t = threadIdx.x, lane = t & 63, w = t >> 6;   // 8 waves
  int rw = w >> 2, cw = w & 3;                      // 2x4 wave grid on 128x256
  int m0 = hs * 128 + rw * 64;
  int n0 = cw * 64;
  int l15 = lane & 15, l4 = lane >> 4;
  int s_cq  = (lane >> 3) | (w << 3);       // 0..63: which c-quad
  int s_hpl = lane & 7;                     // low 3 bits of hw-pair
  floatx4 acc[4][4];
  floatx4 z = {0.f, 0.f, 0.f, 0.f};
#pragma unroll
  for (int i = 0; i < 4; i++)
#pragma unroll
    for (int j = 0; j < 4; j++) acc[i][j] = z;

  // stage phase 0 directly (load -> cast -> ds_write), bits identical to R5
#pragma unroll
  for (int e = 0; e < 8; e++) {
    int hp = s_hpl | (e << 3);
    const float* src = xv + ((size_t)(hp * 2)) * C_ + s_cq * 4;
    float4 v0 = *(const float4*)src;
    float4 v1 = *(const float4*)(src + C_);
    float a0[4] = {v0.x, v0.y, v0.z, v0.w};
    float a1[4] = {v1.x, v1.y, v1.z, v1.w};
#pragma unroll
    for (int i = 0; i < 4; i++) {
      unsigned u = (unsigned)f2bf(a0[i]) | ((unsigned)f2bf(a1[i]) << 16);
      int r = s_cq * 4 + i;
      int slot = (hp >> 2) ^ (r & 15);
      ((unsigned*)Pt)[r * 64 + slot * 4 + (hp & 3)] = u;
    }
  }
  __syncthreads();

  float4 pA[8], pB[8];
  for (int ph = 0; ph < 4; ph++) {
    if (ph < 3) {
      // prefetch next phase's globals into registers (hidden under MFMA)
#pragma unroll
      for (int e = 0; e < 8; e++) {
        int hp = s_hpl | (e << 3);
        const float* src = xv + ((size_t)((ph + 1) * 128 + hp * 2)) * C_ + s_cq * 4;
        pA[e] = *(const float4*)src;
        pB[e] = *(const float4*)(src + C_);
      }
    }
#pragma unroll
    for (int kk = 0; kk < 4; kk++) {       // 4 k-steps of 32 per phase
      short8 af[4], bfv[4];
      int oct = kk * 4 + l4;
#pragma unroll
      for (int tm = 0; tm < 4; tm++) {
        int row = m0 + tm * 16 + l15;
        af[tm] = *(const short8*)(Pt + row * 128 + ((oct ^ (row & 15)) * 8));
      }
#pragma unroll
      for (int tn = 0; tn < 4; tn++) {
        int row = n0 + tn * 16 + l15;
        bfv[tn] = *(const short8*)(Pt + row * 128 + ((oct ^ (row & 15)) * 8));
      }
#pragma unroll
      for (int tm = 0; tm < 4; tm++)
#pragma unroll
        for (int tn = 0; tn < 4; tn++)
          acc[tm][tn] = __builtin_amdgcn_mfma_f32_16x16x32_bf16(af[tm], bfv[tn],
                                                                acc[tm][tn], 0, 0, 0);
    }
    if (ph < 3) {
      __syncthreads();                     // everyone done reading Pt(ph)
#pragma unroll
      for (int e = 0; e < 8; e++) {
        int hp = s_hpl | (e << 3);
        float a0[4] = {pA[e].x, pA[e].y, pA[e].z, pA[e].w};
        float a1[4] = {pB[e].x, pB[e].y, pB[e].z, pB[e].w};
#pragma unroll
        for (int i = 0; i < 4; i++) {
          unsigned u = (unsigned)f2bf(a0[i]) | ((unsigned)f2bf(a1[i]) << 16);
          int r = s_cq * 4 + i;
          int slot = (hp >> 2) ^ (r & 15);
          ((unsigned*)Pt)[r * 64 + slot * 4 + (hp & 3)] = u;
        }
      }
      __syncthreads();                     // Pt(ph+1) ready
    }
  }
  // epilogue: streaming fp32 partial half-tile [b][ks][m 128-half][256]
  float* pb = part + (size_t)(b * 32 + ks) * 65536;
#pragma unroll
  for (int tm = 0; tm < 4; tm++)
#pragma unroll
    for (int tn = 0; tn < 4; tn++)
#pragma unroll
      for (int r = 0; r < 4; r++) {
        int m = m0 + tm * 16 + l4 * 4 + r;   // C/D: row=(lane>>4)*4+reg
        int n = n0 + tn * 16 + l15;          //      col=lane&15
        pb[m * 256 + n] = acc[tm][tn][r];
      }
}

// ---------------------------------------------------------------------------
// K_MEGA: sred + gemm_sw + fuse + w3 in one launch, grid 256 x 256 thr,
// manual grid barriers between phases. Phase bodies are the R5 kernels
// verbatim (bitwise-identical results). LDS is a union (max 131 KiB -> one
// block per CU -> all 256 blocks co-resident, barrier is safe).
// ---------------------------------------------------------------------------
__global__ __launch_bounds__(256) void k_mega(const float* __restrict__ part,
                                              float* __restrict__ S,
                                              const float* __restrict__ Wq,
                                              const float* __restrict__ Wk,
                                              float* __restrict__ SWq,
                                              float* __restrict__ SWk,
                                              const float* __restrict__ Wout,
                                              const float* __restrict__ Wv,
                                              float* __restrict__ U,
                                              unsigned short* __restrict__ W3bT,
                                              unsigned* __restrict__ bars) {
  __shared__ union {
    struct { float Ast[16][68]; float Bs[16][68]; } g;
    struct { float Wqh[256][32]; float Wkh[256][32];
             float SWqh[256][32]; float SWkh[256][32];
             float Lg[32][33]; float qp[8][32]; float kp[8][32];
             float qin[32]; float kin[32]; } f;
  } sh;
  int bid = blockIdx.x, t = threadIdx.x;

  // ---- phase 1: reduce 32 K-partials -> S (float4 per thread) ----
  {
    int g = bid * 256 + t;                  // 0..65535 float4 slots
    int b = g >> 14, off = (g & 16383) * 4;
    const float* p = part + ((size_t)b << 21) + off;
    float4 s = {0.f, 0.f, 0.f, 0.f};
#pragma unroll
    for (int k = 0; k < 32; k++) {
      float4 v = *(const float4*)(p + ((size_t)k << 16));
      s.x += v.x; s.y += v.y; s.z += v.z; s.w += v.w;
    }
    *(float4*)(S + ((size_t)b << 16) + off) = s;
  }
  gridbar(bars + 0);

  // ---- phase 2: SWq = S@Wq, SWk = S@Wk (bid < 128, old k_gemm_sw) ----
  if (bid < 128) {
    int nt = bid & 7, mt = (bid >> 3) & 3, b = bid >> 5;
    int mb = mt * 64;
    const float* Wsel = (nt < 4) ? Wq : Wk;
    int nb = (nt & 3) * 64;
    int tx = t & 15, ty = t >> 4;
    float acc[4][4] = {};
    for (int kt = 0; kt < 16; kt++) {
      {
        int row = t >> 2, kq = t & 3;
        float4 v = *(const float4*)(S + ((size_t)(b * C_ + mb + row)) * C_ + kt * 16 + kq * 4);
        sh.g.Ast[kq * 4 + 0][row] = v.x; sh.g.Ast[kq * 4 + 1][row] = v.y;
        sh.g.Ast[kq * 4 + 2][row] = v.z; sh.g.Ast[kq * 4 + 3][row] = v.w;
      }
      {
        int kk = t >> 4, n4 = t & 15;
        float4 v = *(const float4*)(Wsel + ((size_t)(kt * 16 + kk)) * C_ + nb + n4 * 4);
        *(float4*)&sh.g.Bs[kk][n4 * 4] = v;
      }
      __syncthreads();
#pragma unroll
      for (int k = 0; k < 16; k++) {
        float4 a4 = *(const float4*)&sh.g.Ast[k][ty * 4];
        float4 b4 = *(const float4*)&sh.g.Bs[k][tx * 4];
        float a[4] = {a4.x, a4.y, a4.z, a4.w};
        float bb[4] = {b4.x, b4.y, b4.z, b4.w};
#pragma unroll
        for (int i = 0; i < 4; i++)
#pragma unroll
          for (int j = 0; j < 4; j++) acc[i][j] += a[i] * bb[j];
      }
      __syncthreads();
    }
#pragma unroll
    for (int i = 0; i < 4; i++)
#pragma unroll
      for (int j = 0; j < 4; j++) {
        int row = mb + ty * 4 + i;
        int ng = nt * 64 + tx * 4 + j;
        if (ng < 256) SWq[((size_t)(b * C_ + row)) * C_ + ng] = acc[i][j];
        else          SWk[((size_t)(b * C_ + row)) * C_ + ng - 256] = acc[i][j];
      }
  }
  gridbar(bars + 1);

  // ---- phase 3: fused G + norms + softmax + U (bid < 32, old k_fuse) ----
  if (bid < 32) {
    int b = bid >> 3, h = bid & 7;
    int col = t & 31, rgrp = t >> 5;
    for (int r0 = 0; r0 < 256; r0 += 8) {
      int row = r0 + rgrp;
      sh.f.Wqh[row][col]  = Wq[(size_t)row * C_ + h * 32 + col];
      sh.f.Wkh[row][col]  = Wk[(size_t)row * C_ + h * 32 + col];
      sh.f.SWqh[row][col] = SWq[((size_t)(b * C_ + row)) * C_ + h * 32 + col];
      sh.f.SWkh[row][col] = SWk[((size_t)(b * C_ + row)) * C_ + h * 32 + col];
    }
    __syncthreads();
    {
      float g[4] = {0.f, 0.f, 0.f, 0.f};
      for (int k = 0; k < 256; k++) {
        float swk = sh.f.SWkh[k][col];
#pragma unroll
        for (int r = 0; r < 4; r++) g[r] += sh.f.Wqh[k][rgrp + 8 * r] * swk;
      }
#pragma unroll
      for (int r = 0; r < 4; r++) sh.f.Lg[rgrp + 8 * r][col] = g[r];
    }
    {
      float sq = 0.f, sk = 0.f;
      for (int k = rgrp * 32; k < rgrp * 32 + 32; k++) {
        sq += sh.f.Wqh[k][col] * sh.f.SWqh[k][col];
        sk += sh.f.Wkh[k][col] * sh.f.SWkh[k][col];
      }
      sh.f.qp[rgrp][col] = sq;
      sh.f.kp[rgrp][col] = sk;
    }
    __syncthreads();
    if (t < 32) {
      float a = 0.f;
#pragma unroll
      for (int p = 0; p < 8; p++) a += sh.f.qp[p][t];
      sh.f.qin[t] = rsqrtf(a);
    } else if (t < 64) {
      int j = t - 32;
      float a = 0.f;
#pragma unroll
      for (int p = 0; p < 8; p++) a += sh.f.kp[p][j];
      sh.f.kin[j] = rsqrtf(a);
    }
    __syncthreads();
    if (t < 32) {
      float row[32];
      float mx = -1e30f;
#pragma unroll
      for (int j = 0; j < 32; j++) {
        row[j] = sh.f.Lg[t][j] * sh.f.qin[t] * sh.f.kin[j] * 0.0078125f;
        mx = fmaxf(mx, row[j]);
      }
      float sum = 0.f;
#pragma unroll
      for (int j = 0; j < 32; j++) { row[j] = __expf(row[j] - mx); sum += row[j]; }
      float inv = 1.0f / sum;
#pragma unroll
      for (int j = 0; j < 32; j++) sh.f.Lg[t][j] = row[j] * inv;
    }
    __syncthreads();
    float (*Wo)[256] = reinterpret_cast<float(*)[256]>(&sh.f.Wqh[0][0]);
#pragma unroll
    for (int r = 0; r < 32; r++) Wo[r][t] = Wout[((size_t)(h * 32 + r)) * C_ + t];
    __syncthreads();
    for (int j = 0; j < 32; j++) {
      float a = 0.f;
#pragma unroll
      for (int i2 = 0; i2 < 32; i2++) a += sh.f.Lg[i2][j] * Wo[i2][t];
      U[((size_t)(b * C_ + h * 32 + j)) * C_ + t] = a;
    }
  }
  gridbar(bars + 2);

  // ---- phase 4: W3 = Wv @ U[b] -> bf16 W3bT (bid < 64, old k_gemm_w3) ----
  if (bid < 64) {
    int nt = bid & 3, mt = (bid >> 2) & 3, b = bid >> 4;
    int mb = mt * 64, nb = nt * 64;
    int tx = t & 15, ty = t >> 4;
    float acc[4][4] = {};
    for (int kt = 0; kt < 16; kt++) {
      {
        int row = t >> 2, kq = t & 3;
        float4 v = *(const float4*)(Wv + ((size_t)(mb + row)) * C_ + kt * 16 + kq * 4);
        sh.g.Ast[kq * 4 + 0][row] = v.x; sh.g.Ast[kq * 4 + 1][row] = v.y;
        sh.g.Ast[kq * 4 + 2][row] = v.z; sh.g.Ast[kq * 4 + 3][row] = v.w;
      }
      {
        int kk = t >> 4, n4 = t & 15;
        float4 v = *(const float4*)(U + ((size_t)(b * C_ + kt * 16 + kk)) * C_ + nb + n4 * 4);
        *(float4*)&sh.g.Bs[kk][n4 * 4] = v;
      }
      __syncthreads();
#pragma unroll
      for (int k = 0; k < 16; k++) {
        float4 a4 = *(const float4*)&sh.g.Ast[k][ty * 4];
        float4 b4 = *(const float4*)&sh.g.Bs[k][tx * 4];
        float a[4] = {a4.x, a4.y, a4.z, a4.w};
        float bb[4] = {b4.x, b4.y, b4.z, b4.w};
#pragma unroll
        for (int i = 0; i < 4; i++)
#pragma unroll
          for (int j = 0; j < 4; j++) acc[i][j] += a[i] * bb[j];
      }
      __syncthreads();
    }
#pragma unroll
    for (int i = 0; i < 4; i++)
#pragma unroll
      for (int j = 0; j < 4; j++)
        W3bT[((size_t)(b * C_ + nb + tx * 4 + j)) * C_ + mb + ty * 4 + i] = f2bf(acc[i][j]);
  }
}

// ---------------------------------------------------------------------------
// K4: out = x @ W3[b], fp32 out. grid 512 = mtile. BN=256 per block.
// A-fragments read DIRECTLY from fp32 x (L3-hot) + register f2bf; B staged
// via swizzled global_load_lds (8-slot rows). BK=64, 4 stages.
// ---------------------------------------------------------------------------
__global__ __launch_bounds__(256) void k_out(const float* __restrict__ x,
                                             const unsigned short* __restrict__ W3bT,
                                             float* __restrict__ out) {
  __shared__ unsigned short Bt[256 * 64];   // 32 KiB
  int mtile = blockIdx.x;
  int b = mtile >> 7;
  const float* Ax = x + (size_t)mtile * 128 * C_;
  const unsigned short* Bb = W3bT + (size_t)b * C_ * C_;
  int t = threadIdx.x, lane = t & 63, w = t >> 6;
  int hf = w >> 1, c2 = w & 1;
  int l8 = lane >> 3, l7 = lane & 7;
  int srcoct = l7 ^ l8;
  int l15 = lane & 15, l4 = lane >> 4;
  floatx4 acc[4][8];
  floatx4 z = {0.f, 0.f, 0.f, 0.f};
#pragma unroll
  for (int i = 0; i < 4; i++)
#pragma unroll
    for (int j = 0; j < 8; j++) acc[i][j] = z;
  for (int s = 0; s < 4; s++) {
    if (s) __syncthreads();
#pragma unroll
    for (int i = 0; i < 8; i++) {
      int ib = w * 8 + i;                  // 0..31 -> B rows 0..255
      int row = ib * 8 + l8;
      gl_lds16(Bb + (size_t)row * C_ + s * 64 + srcoct * 8, Bt + ib * 512);
    }
    __syncthreads();
#pragma unroll
    for (int kk = 0; kk < 2; kk++) {
      short8 af[4], bfv[8];
      int oct = kk * 4 + l4;
#pragma unroll
      for (int tm = 0; tm < 4; tm++) {
        int row = hf * 64 + tm * 16 + l15;
        const float* p = Ax + (size_t)row * C_ + s * 64 + oct * 8;
        float4 u0 = *(const float4*)p;
        float4 u1 = *(const float4*)(p + 4);
        short8 v;
        v[0] = (short)f2bf(u0.x); v[1] = (short)f2bf(u0.y);
        v[2] = (short)f2bf(u0.z); v[3] = (short)f2bf(u0.w);
        v[4] = (short)f2bf(u1.x); v[5] = (short)f2bf(u1.y);
        v[6] = (short)f2bf(u1.z); v[7] = (short)f2bf(u1.w);
        af[tm] = v;
      }
#pragma unroll
      for (int tn = 0; tn < 8; tn++) {
        int row = c2 * 128 + tn * 16 + l15;
        bfv[tn] = *(const short8*)(Bt + row * 64 + ((oct ^ (row & 7)) * 8));
      }
#pragma unroll
      for (int tm = 0; tm < 4; tm++)
#pragma unroll
        for (int tn = 0; tn < 8; tn++)
          acc[tm][tn] = __builtin_amdgcn_mfma_f32_16x16x32_bf16(af[tm], bfv[tn],
                                                                acc[tm][tn], 0, 0, 0);
    }
  }
  float* ob = out + (size_t)mtile * 128 * C_;
#pragma unroll
  for (int tm = 0; tm < 4; tm++)
#pragma unroll
    for (int tn = 0; tn < 8; tn++)
#pragma unroll
      for (int r = 0; r < 4; r++) {
        int m = hf * 64 + tm * 16 + l4 * 4 + r;
        int n = c2 * 128 + tn * 16 + l15;
        ob[(size_t)m * C_ + n] = acc[tm][tn][r];
      }
}

// ---------------------------------------------------------------------------
extern "C" void kernel_launch(void* const* d_in, const int* in_sizes, int n_in,
                              void* d_out, int out_size, void* d_ws, size_t ws_size,
                              hipStream_t stream) {
  const float* x    = (const float*)d_in[0];
  const float* Wq   = (const float*)d_in[1];
  const float* Wk   = (const float*)d_in[2];
  const float* Wv   = (const float*)d_in[3];
  const float* Wout = (const float*)d_in[4];
  float* out = (float*)d_out;

  // workspace carve-up (~36.5 MiB)
  float* part = (float*)d_ws;                           // 4*32*256*256 fp32 = 32 MiB
  float* S    = part + (size_t)8388608;                 // 1 MiB
  float* SWq  = S + 262144;                             // 1 MiB
  float* SWk  = SWq + 262144;                           // 1 MiB
  float* U    = SWk + 262144;                           // 1 MiB
  unsigned short* W3bT = (unsigned short*)(U + 262144); // 512 KiB
  unsigned* bars = (unsigned*)(W3bT + 262144);          // 8 counters

  k_sgemm<<<dim3(256), dim3(512), 0, stream>>>(x, part, bars);
  k_mega<<<dim3(256), dim3(256), 0, stream>>>(part, S, Wq, Wk, SWq, SWk,
                                              Wout, Wv, U, W3bT, bars);
  k_out<<<dim3(512), dim3(256), 0, stream>>>(x, W3bT, out);
}

// Round 4
// 219.923 us; speedup vs baseline: 1.3297x; 1.3297x over previous
//
#include <hip/hip_runtime.h>

// SpectralMultiHeadAttention on MI355X (gfx950)
// b=4, hw=16384, c=256, heads=8, dh=32.
// Reformulation: S[b] = x^T x (256x256);  G = Wq^T S Wk;  qss = diag(Wq^T S Wq);
// kss = diag(Wk^T S Wk);  A = softmax(G_blocks / (nq nk sqrt(hw)));
// out = x @ (Wv @ Abig^T @ Wout).   q/k/v never materialized.
// R7: R6's grid-barrier mega-fusion REVERTED (k_mega was 146us of barrier
//     idle: VALUBusy 2.3%, HBM 2.6% -- AGENT-scope barriers cost ~45us each,
//     far worse than launches). Kept R6's two real wins on the R5 chain:
//     (a) k_sgemm grid 256 (output half-split, same K-chain -> S bitwise
//         identical) + register prefetch of next staging phase under MFMA;
//     (b) k_sred float4 (grid 256, same per-element add order).

#define B_   4
#define HW_  16384
#define C_   256

typedef __attribute__((ext_vector_type(8))) short short8;
typedef __attribute__((ext_vector_type(4))) float floatx4;

__device__ __forceinline__ unsigned short f2bf(float f) {
  unsigned u = __builtin_bit_cast(unsigned, f);
  u += 0x7FFFu + ((u >> 16) & 1u);          // round-to-nearest-even
  return (unsigned short)(u >> 16);
}

__device__ __forceinline__ void gl_lds16(const unsigned short* g, unsigned short* l) {
  __builtin_amdgcn_global_load_lds(
      (const __attribute__((address_space(1))) unsigned int*)g,
      (__attribute__((address_space(3))) unsigned int*)l, 16, 0, 0);
}

// ---------------------------------------------------------------------------
// K2: S partials. grid 256 = half(1b) | ks(5b) | b(2b), 512 thr. Each block
// stages the FULL 256c x 128hw bf16 panel (4 phases over its 512-hw chunk,
// bits identical to R5) but computes only a 128-row half of the 256x256
// output -> all 256 CUs busy, identical K-chain per output element.
// Register prefetch: next phase's 16 float4 issued before current compute.
// ---------------------------------------------------------------------------
__global__ __launch_bounds__(512) void k_sgemm(const float* __restrict__ x,
                                               float* __restrict__ part) {
  __shared__ unsigned short Pt[256 * 128];   // 64 KiB
  int bid = blockIdx.x;
  int hs = bid & 1, ks = (bid >> 1) & 31, b = bid >> 6;
  const float* xv = x + ((size_t)(b * HW_ + ks * 512)) * C_;
  int t = threadIdx.x, lane = t & 63, w = t >> 6;   // 8 waves
  int rw = w >> 2, cw = w & 3;                      // 2x4 wave grid on 128x256
  int m0 = hs * 128 + rw * 64;
  int n0 = cw * 64;
  int l15 = lane & 15, l4 = lane >> 4;
  int s_cq  = (lane >> 3) | (w << 3);       // 0..63: which c-quad
  int s_hpl = lane & 7;                     // low 3 bits of hw-pair
  floatx4 acc[4][4];
  floatx4 z = {0.f, 0.f, 0.f, 0.f};
#pragma unroll
  for (int i = 0; i < 4; i++)
#pragma unroll
    for (int j = 0; j < 4; j++) acc[i][j] = z;

  // stage phase 0 directly (load -> cast -> ds_write), bits identical to R5
#pragma unroll
  for (int e = 0; e < 8; e++) {
    int hp = s_hpl | (e << 3);
    const float* src = xv + ((size_t)(hp * 2)) * C_ + s_cq * 4;
    float4 v0 = *(const float4*)src;
    float4 v1 = *(const float4*)(src + C_);
    float a0[4] = {v0.x, v0.y, v0.z, v0.w};
    float a1[4] = {v1.x, v1.y, v1.z, v1.w};
#pragma unroll
    for (int i = 0; i < 4; i++) {
      unsigned u = (unsigned)f2bf(a0[i]) | ((unsigned)f2bf(a1[i]) << 16);
      int r = s_cq * 4 + i;
      int slot = (hp >> 2) ^ (r & 15);
      ((unsigned*)Pt)[r * 64 + slot * 4 + (hp & 3)] = u;
    }
  }
  __syncthreads();

  float4 pA[8], pB[8];
  for (int ph = 0; ph < 4; ph++) {
    if (ph < 3) {
      // prefetch next phase's globals into registers (hidden under MFMA)
#pragma unroll
      for (int e = 0; e < 8; e++) {
        int hp = s_hpl | (e << 3);
        const float* src = xv + ((size_t)((ph + 1) * 128 + hp * 2)) * C_ + s_cq * 4;
        pA[e] = *(const float4*)src;
        pB[e] = *(const float4*)(src + C_);
      }
    }
#pragma unroll
    for (int kk = 0; kk < 4; kk++) {       // 4 k-steps of 32 per phase
      short8 af[4], bfv[4];
      int oct = kk * 4 + l4;
#pragma unroll
      for (int tm = 0; tm < 4; tm++) {
        int row = m0 + tm * 16 + l15;
        af[tm] = *(const short8*)(Pt + row * 128 + ((oct ^ (row & 15)) * 8));
      }
#pragma unroll
      for (int tn = 0; tn < 4; tn++) {
        int row = n0 + tn * 16 + l15;
        bfv[tn] = *(const short8*)(Pt + row * 128 + ((oct ^ (row & 15)) * 8));
      }
#pragma unroll
      for (int tm = 0; tm < 4; tm++)
#pragma unroll
        for (int tn = 0; tn < 4; tn++)
          acc[tm][tn] = __builtin_amdgcn_mfma_f32_16x16x32_bf16(af[tm], bfv[tn],
                                                                acc[tm][tn], 0, 0, 0);
    }
    if (ph < 3) {
      __syncthreads();                     // everyone done reading Pt(ph)
#pragma unroll
      for (int e = 0; e < 8; e++) {
        int hp = s_hpl | (e << 3);
        float a0[4] = {pA[e].x, pA[e].y, pA[e].z, pA[e].w};
        float a1[4] = {pB[e].x, pB[e].y, pB[e].z, pB[e].w};
#pragma unroll
        for (int i = 0; i < 4; i++) {
          unsigned u = (unsigned)f2bf(a0[i]) | ((unsigned)f2bf(a1[i]) << 16);
          int r = s_cq * 4 + i;
          int slot = (hp >> 2) ^ (r & 15);
          ((unsigned*)Pt)[r * 64 + slot * 4 + (hp & 3)] = u;
        }
      }
      __syncthreads();                     // Pt(ph+1) ready
    }
  }
  // epilogue: streaming fp32 partial half-tile [b][ks][m 128-half][256]
  float* pb = part + (size_t)(b * 32 + ks) * 65536;
#pragma unroll
  for (int tm = 0; tm < 4; tm++)
#pragma unroll
    for (int tn = 0; tn < 4; tn++)
#pragma unroll
      for (int r = 0; r < 4; r++) {
        int m = m0 + tm * 16 + l4 * 4 + r;   // C/D: row=(lane>>4)*4+reg
        int n = n0 + tn * 16 + l15;          //      col=lane&15
        pb[m * 256 + n] = acc[tm][tn][r];
      }
}

// K2r: reduce 32 K-partials -> S fp32 [b][256][256]. grid 256 x 256, float4.
// Same per-element scalar add order as R5 -> bitwise identical.
__global__ __launch_bounds__(256) void k_sred(const float* __restrict__ part,
                                              float* __restrict__ S) {
  int g = blockIdx.x * 256 + threadIdx.x;     // 0..65535 float4 slots
  int b = g >> 14, off = (g & 16383) * 4;
  const float* p = part + ((size_t)b << 21) + off;
  float4 s = {0.f, 0.f, 0.f, 0.f};
#pragma unroll
  for (int k = 0; k < 32; k++) {
    float4 v = *(const float4*)(p + ((size_t)k << 16));
    s.x += v.x; s.y += v.y; s.z += v.z; s.w += v.w;
  }
  *(float4*)(S + ((size_t)b << 16) + off) = s;
}

// ---------------------------------------------------------------------------
// K3a: SWq = S@Wq, SWk = S@Wk (fp32, 64x64 tiles). grid 128 = b(4)*mt(4)*nt(8).
// A staged transposed [k][m] (pad 68 keeps float4 alignment, 2-way banks)
// so the inner loop is 2x ds_read_b128 per k instead of 8x ds_read_b32.
// ---------------------------------------------------------------------------
__global__ __launch_bounds__(256) void k_gemm_sw(const float* __restrict__ S,
                                                 const float* __restrict__ Wq,
                                                 const float* __restrict__ Wk,
                                                 float* __restrict__ SWq,
                                                 float* __restrict__ SWk) {
  __shared__ float Ast[16][68];
  __shared__ float Bs[16][68];
  int bid = blockIdx.x;
  int nt = bid & 7, mt = (bid >> 3) & 3, b = bid >> 5;
  int mb = mt * 64;
  const float* Wsel = (nt < 4) ? Wq : Wk;
  int nb = (nt & 3) * 64;
  int t = threadIdx.x, tx = t & 15, ty = t >> 4;
  float acc[4][4] = {};
  for (int kt = 0; kt < 16; kt++) {
    {
      int row = t >> 2, kq = t & 3;
      float4 v = *(const float4*)(S + ((size_t)(b * C_ + mb + row)) * C_ + kt * 16 + kq * 4);
      Ast[kq * 4 + 0][row] = v.x; Ast[kq * 4 + 1][row] = v.y;
      Ast[kq * 4 + 2][row] = v.z; Ast[kq * 4 + 3][row] = v.w;
    }
    {
      int kk = t >> 4, n4 = t & 15;
      float4 v = *(const float4*)(Wsel + ((size_t)(kt * 16 + kk)) * C_ + nb + n4 * 4);
      *(float4*)&Bs[kk][n4 * 4] = v;
    }
    __syncthreads();
#pragma unroll
    for (int k = 0; k < 16; k++) {
      float4 a4 = *(const float4*)&Ast[k][ty * 4];
      float4 b4 = *(const float4*)&Bs[k][tx * 4];
      float a[4] = {a4.x, a4.y, a4.z, a4.w};
      float bb[4] = {b4.x, b4.y, b4.z, b4.w};
#pragma unroll
      for (int i = 0; i < 4; i++)
#pragma unroll
        for (int j = 0; j < 4; j++) acc[i][j] += a[i] * bb[j];
    }
    __syncthreads();
  }
#pragma unroll
  for (int i = 0; i < 4; i++)
#pragma unroll
    for (int j = 0; j < 4; j++) {
      int row = mb + ty * 4 + i;
      int ng = nt * 64 + tx * 4 + j;
      if (ng < 256) SWq[((size_t)(b * C_ + row)) * C_ + ng] = acc[i][j];
      else          SWk[((size_t)(b * C_ + row)) * C_ + ng - 256] = acc[i][j];
    }
}

// ---------------------------------------------------------------------------
// K3f: fused G_h + norms + softmax + U_h. grid 32 = (b,h), 256 thr.
// ---------------------------------------------------------------------------
__global__ __launch_bounds__(256) void k_fuse(const float* __restrict__ Wq,
                                              const float* __restrict__ Wk,
                                              const float* __restrict__ SWq,
                                              const float* __restrict__ SWk,
                                              const float* __restrict__ Wout,
                                              float* __restrict__ U) {
  __shared__ float Wqh[256][32];    // 32 KiB (reused as Wo[32][256] for U phase)
  __shared__ float Wkh[256][32];
  __shared__ float SWqh[256][32];
  __shared__ float SWkh[256][32];   // total 128 KiB
  __shared__ float Lg[32][33];
  __shared__ float qp[8][32], kp[8][32], qin[32], kin[32];
  int b = blockIdx.x >> 3, h = blockIdx.x & 7;
  int t = threadIdx.x;
  int col = t & 31, rgrp = t >> 5;               // 8 rows per sweep
  for (int r0 = 0; r0 < 256; r0 += 8) {
    int row = r0 + rgrp;
    Wqh[row][col]  = Wq[(size_t)row * C_ + h * 32 + col];
    Wkh[row][col]  = Wk[(size_t)row * C_ + h * 32 + col];
    SWqh[row][col] = SWq[((size_t)(b * C_ + row)) * C_ + h * 32 + col];
    SWkh[row][col] = SWk[((size_t)(b * C_ + row)) * C_ + h * 32 + col];
  }
  __syncthreads();
  {
    float g[4] = {0.f, 0.f, 0.f, 0.f};
    for (int k = 0; k < 256; k++) {
      float swk = SWkh[k][col];
#pragma unroll
      for (int r = 0; r < 4; r++) g[r] += Wqh[k][rgrp + 8 * r] * swk;
    }
#pragma unroll
    for (int r = 0; r < 4; r++) Lg[rgrp + 8 * r][col] = g[r];
  }
  {
    float sq = 0.f, sk = 0.f;
    for (int k = rgrp * 32; k < rgrp * 32 + 32; k++) {
      sq += Wqh[k][col] * SWqh[k][col];
      sk += Wkh[k][col] * SWkh[k][col];
    }
    qp[rgrp][col] = sq;
    kp[rgrp][col] = sk;
  }
  __syncthreads();
  if (t < 32) {
    float a = 0.f;
#pragma unroll
    for (int p = 0; p < 8; p++) a += qp[p][t];
    qin[t] = rsqrtf(a);
  } else if (t < 64) {
    int j = t - 32;
    float a = 0.f;
#pragma unroll
    for (int p = 0; p < 8; p++) a += kp[p][j];
    kin[j] = rsqrtf(a);
  }
  __syncthreads();
  if (t < 32) {
    float row[32];
    float mx = -1e30f;
#pragma unroll
    for (int j = 0; j < 32; j++) {
      row[j] = Lg[t][j] * qin[t] * kin[j] * 0.0078125f;   // /sqrt(16384)
      mx = fmaxf(mx, row[j]);
    }
    float sum = 0.f;
#pragma unroll
    for (int j = 0; j < 32; j++) { row[j] = __expf(row[j] - mx); sum += row[j]; }
    float inv = 1.0f / sum;
#pragma unroll
    for (int j = 0; j < 32; j++) Lg[t][j] = row[j] * inv;
  }
  __syncthreads();
  float (*Wo)[256] = reinterpret_cast<float(*)[256]>(&Wqh[0][0]);
#pragma unroll
  for (int r = 0; r < 32; r++) Wo[r][t] = Wout[((size_t)(h * 32 + r)) * C_ + t];
  __syncthreads();
  for (int j = 0; j < 32; j++) {
    float a = 0.f;
#pragma unroll
    for (int i2 = 0; i2 < 32; i2++) a += Lg[i2][j] * Wo[i2][t];
    U[((size_t)(b * C_ + h * 32 + j)) * C_ + t] = a;
  }
}

// ---------------------------------------------------------------------------
// K3e: W3 = Wv @ U[b], emitted transposed bf16: W3bT[b][n][c]. grid 64.
// ---------------------------------------------------------------------------
__global__ __launch_bounds__(256) void k_gemm_w3(const float* __restrict__ Wv,
                                                 const float* __restrict__ U,
                                                 unsigned short* __restrict__ W3bT) {
  __shared__ float Ast[16][68];
  __shared__ float Bs[16][68];
  int bid = blockIdx.x;
  int nt = bid & 3, mt = (bid >> 2) & 3, b = bid >> 4;
  int mb = mt * 64, nb = nt * 64;
  int t = threadIdx.x, tx = t & 15, ty = t >> 4;
  float acc[4][4] = {};
  for (int kt = 0; kt < 16; kt++) {
    {
      int row = t >> 2, kq = t & 3;
      float4 v = *(const float4*)(Wv + ((size_t)(mb + row)) * C_ + kt * 16 + kq * 4);
      Ast[kq * 4 + 0][row] = v.x; Ast[kq * 4 + 1][row] = v.y;
      Ast[kq * 4 + 2][row] = v.z; Ast[kq * 4 + 3][row] = v.w;
    }
    {
      int kk = t >> 4, n4 = t & 15;
      float4 v = *(const float4*)(U + ((size_t)(b * C_ + kt * 16 + kk)) * C_ + nb + n4 * 4);
      *(float4*)&Bs[kk][n4 * 4] = v;
    }
    __syncthreads();
#pragma unroll
    for (int k = 0; k < 16; k++) {
      float4 a4 = *(const float4*)&Ast[k][ty * 4];
      float4 b4 = *(const float4*)&Bs[k][tx * 4];
      float a[4] = {a4.x, a4.y, a4.z, a4.w};
      float bb[4] = {b4.x, b4.y, b4.z, b4.w};
#pragma unroll
      for (int i = 0; i < 4; i++)
#pragma unroll
        for (int j = 0; j < 4; j++) acc[i][j] += a[i] * bb[j];
    }
    __syncthreads();
  }
#pragma unroll
  for (int i = 0; i < 4; i++)
#pragma unroll
    for (int j = 0; j < 4; j++)
      W3bT[((size_t)(b * C_ + nb + tx * 4 + j)) * C_ + mb + ty * 4 + i] = f2bf(acc[i][j]);
}

// ---------------------------------------------------------------------------
// K4: out = x @ W3[b], fp32 out. grid 512 = mtile. BN=256 per block.
// A-fragments read DIRECTLY from fp32 x (L3-hot) + register f2bf; B staged
// via swizzled global_load_lds (8-slot rows). BK=64, 4 stages.
// ---------------------------------------------------------------------------
__global__ __launch_bounds__(256) void k_out(const float* __restrict__ x,
                                             const unsigned short* __restrict__ W3bT,
                                             float* __restrict__ out) {
  __shared__ unsigned short Bt[256 * 64];   // 32 KiB
  int mtile = blockIdx.x;
  int b = mtile >> 7;
  const float* Ax = x + (size_t)mtile * 128 * C_;
  const unsigned short* Bb = W3bT + (size_t)b * C_ * C_;
  int t = threadIdx.x, lane = t & 63, w = t >> 6;
  int hf = w >> 1, c2 = w & 1;
  int l8 = lane >> 3, l7 = lane & 7;
  int srcoct = l7 ^ l8;
  int l15 = lane & 15, l4 = lane >> 4;
  floatx4 acc[4][8];
  floatx4 z = {0.f, 0.f, 0.f, 0.f};
#pragma unroll
  for (int i = 0; i < 4; i++)
#pragma unroll
    for (int j = 0; j < 8; j++) acc[i][j] = z;
  for (int s = 0; s < 4; s++) {
    if (s) __syncthreads();
#pragma unroll
    for (int i = 0; i < 8; i++) {
      int ib = w * 8 + i;                  // 0..31 -> B rows 0..255
      int row = ib * 8 + l8;
      gl_lds16(Bb + (size_t)row * C_ + s * 64 + srcoct * 8, Bt + ib * 512);
    }
    __syncthreads();
#pragma unroll
    for (int kk = 0; kk < 2; kk++) {
      short8 af[4], bfv[8];
      int oct = kk * 4 + l4;
#pragma unroll
      for (int tm = 0; tm < 4; tm++) {
        int row = hf * 64 + tm * 16 + l15;
        const float* p = Ax + (size_t)row * C_ + s * 64 + oct * 8;
        float4 u0 = *(const float4*)p;
        float4 u1 = *(const float4*)(p + 4);
        short8 v;
        v[0] = (short)f2bf(u0.x); v[1] = (short)f2bf(u0.y);
        v[2] = (short)f2bf(u0.z); v[3] = (short)f2bf(u0.w);
        v[4] = (short)f2bf(u1.x); v[5] = (short)f2bf(u1.y);
        v[6] = (short)f2bf(u1.z); v[7] = (short)f2bf(u1.w);
        af[tm] = v;
      }
#pragma unroll
      for (int tn = 0; tn < 8; tn++) {
        int row = c2 * 128 + tn * 16 + l15;
        bfv[tn] = *(const short8*)(Bt + row * 64 + ((oct ^ (row & 7)) * 8));
      }
#pragma unroll
      for (int tm = 0; tm < 4; tm++)
#pragma unroll
        for (int tn = 0; tn < 8; tn++)
          acc[tm][tn] = __builtin_amdgcn_mfma_f32_16x16x32_bf16(af[tm], bfv[tn],
                                                                acc[tm][tn], 0, 0, 0);
    }
  }
  float* ob = out + (size_t)mtile * 128 * C_;
#pragma unroll
  for (int tm = 0; tm < 4; tm++)
#pragma unroll
    for (int tn = 0; tn < 8; tn++)
#pragma unroll
      for (int r = 0; r < 4; r++) {
        int m = hf * 64 + tm * 16 + l4 * 4 + r;
        int n = c2 * 128 + tn * 16 + l15;
        ob[(size_t)m * C_ + n] = acc[tm][tn][r];
      }
}

// ---------------------------------------------------------------------------
extern "C" void kernel_launch(void* const* d_in, const int* in_sizes, int n_in,
                              void* d_out, int out_size, void* d_ws, size_t ws_size,
                              hipStream_t stream) {
  const float* x    = (const float*)d_in[0];
  const float* Wq   = (const float*)d_in[1];
  const float* Wk   = (const float*)d_in[2];
  const float* Wv   = (const float*)d_in[3];
  const float* Wout = (const float*)d_in[4];
  float* out = (float*)d_out;

  // workspace carve-up (~36.5 MiB)
  float* part = (float*)d_ws;                           // 4*32*256*256 fp32 = 32 MiB
  float* S    = part + (size_t)8388608;                 // 1 MiB
  float* SWq  = S + 262144;                             // 1 MiB
  float* SWk  = SWq + 262144;                           // 1 MiB
  float* U    = SWk + 262144;                           // 1 MiB
  unsigned short* W3bT = (unsigned short*)(U + 262144); // 512 KiB

  k_sgemm<<<dim3(256), dim3(512), 0, stream>>>(x, part);
  k_sred<<<dim3(256), dim3(256), 0, stream>>>(part, S);
  k_gemm_sw<<<dim3(128), dim3(256), 0, stream>>>(S, Wq, Wk, SWq, SWk);
  k_fuse<<<dim3(32), dim3(256), 0, stream>>>(Wq, Wk, SWq, SWk, Wout, U);
  k_gemm_w3<<<dim3(64), dim3(256), 0, stream>>>(Wv, U, W3bT);
  k_out<<<dim3(512), dim3(256), 0, stream>>>(x, W3bT, out);
}